// Round 1
// baseline (251.280 us; speedup 1.0000x reference)
//
#include <hip/hip_runtime.h>

#define NEV 256   // events
#define NP  512   // particles per event
#define HD  16    // hidden dim
#define GPAD 20   // padded sG row (floats) to spread banks on gathered reads

__device__ __forceinline__ float elu_f(float x) {
    return x > 0.0f ? x : (__expf(x) - 1.0f);
}
__device__ __forceinline__ unsigned umin_(unsigned a, unsigned b) { return a < b ? a : b; }
__device__ __forceinline__ unsigned umax_(unsigned a, unsigned b) { return a > b ? a : b; }

// One DynamicEdgeConv pass. Input features for all NP nodes in sX (+squared
// norms in sSq). Output features for this thread's node returned in fout.
// Uses sG as scratch for the per-node neighbor-projection g_j.
// Contains exactly one __syncthreads (uniform).
__device__ __forceinline__ void conv_pass(
    const float (*__restrict__ sX)[HD], const float* __restrict__ sSq,
    float (*__restrict__ sG)[GPAD],
    const float (*__restrict__ sWcB)[HD], const float (*__restrict__ sWcD)[HD],
    const float* __restrict__ sBc,
    int tid, float* __restrict__ fout)
{
    // own row into registers
    float hi[HD];
#pragma unroll
    for (int q = 0; q < 4; ++q) {
        float4 v = ((const float4*)(&sX[tid][0]))[q];
        hi[4*q+0] = v.x; hi[4*q+1] = v.y; hi[4*q+2] = v.z; hi[4*q+3] = v.w;
    }
    float sqi = sSq[tid];

    // ---- kNN: top-8 smallest d2 over all j, packed (d2 | j) keys ----
    unsigned top[8];
#pragma unroll
    for (int k = 0; k < 8; ++k) top[k] = 0xFFFFFFFFu;

#pragma unroll 4
    for (int j = 0; j < NP; ++j) {
        const float4* r = (const float4*)(&sX[j][0]);   // uniform addr -> broadcast
        float4 va = r[0], vb = r[1], vc = r[2], vd = r[3];
        float sqj = sSq[j];
        float d0 = va.x * hi[0];
        d0 = fmaf(va.y, hi[1], d0); d0 = fmaf(va.z, hi[2], d0); d0 = fmaf(va.w, hi[3], d0);
        float d1 = vb.x * hi[4];
        d1 = fmaf(vb.y, hi[5], d1); d1 = fmaf(vb.z, hi[6], d1); d1 = fmaf(vb.w, hi[7], d1);
        float d2p = vc.x * hi[8];
        d2p = fmaf(vc.y, hi[9], d2p); d2p = fmaf(vc.z, hi[10], d2p); d2p = fmaf(vc.w, hi[11], d2p);
        float d3 = vd.x * hi[12];
        d3 = fmaf(vd.y, hi[13], d3); d3 = fmaf(vd.z, hi[14], d3); d3 = fmaf(vd.w, hi[15], d3);
        float dot = (d0 + d1) + (d2p + d3);
        float dd = fmaf(-2.0f, dot, sqi + sqj);   // ||hi||^2 + ||hj||^2 - 2 hi.hj
        dd = fmaxf(dd, 0.0f);                     // keep uint ordering valid
        unsigned key = (__float_as_uint(dd) & 0xFFFFFE00u) | (unsigned)j;
        // branchless insert into ascending sorted 8 (15 min/max ops)
        top[7] = umax_(top[6], umin_(key, top[7]));
        top[6] = umax_(top[5], umin_(key, top[6]));
        top[5] = umax_(top[4], umin_(key, top[5]));
        top[4] = umax_(top[3], umin_(key, top[4]));
        top[3] = umax_(top[2], umin_(key, top[3]));
        top[2] = umax_(top[1], umin_(key, top[2]));
        top[1] = umax_(top[0], umin_(key, top[1]));
        top[0] = umin_(key, top[0]);
    }

    // ---- per-node projections: g_i = h_i @ WcB ; base_i = h_i @ (WcA-WcB) + bc ----
    float g[HD], base[HD];
#pragma unroll
    for (int c = 0; c < HD; ++c) { g[c] = 0.0f; base[c] = sBc[c]; }
#pragma unroll
    for (int f = 0; f < HD; ++f) {
        float hf = hi[f];
#pragma unroll
        for (int c = 0; c < HD; ++c) {
            g[c]    = fmaf(hf, sWcB[f][c], g[c]);
            base[c] = fmaf(hf, sWcD[f][c], base[c]);
        }
    }
    ((float4*)(&sG[tid][0]))[0] = make_float4(g[0], g[1], g[2], g[3]);
    ((float4*)(&sG[tid][0]))[1] = make_float4(g[4], g[5], g[6], g[7]);
    ((float4*)(&sG[tid][0]))[2] = make_float4(g[8], g[9], g[10], g[11]);
    ((float4*)(&sG[tid][0]))[3] = make_float4(g[12], g[13], g[14], g[15]);
    __syncthreads();   // sG ready for gathers

    // ---- max-aggregate over the 8 neighbors; ELU is monotone -> apply once ----
    float z[HD];
#pragma unroll
    for (int c = 0; c < HD; ++c) z[c] = -3.4e38f;
#pragma unroll
    for (int n = 0; n < 8; ++n) {
        int j = (int)(top[n] & 511u);
        const float4* r = (const float4*)(&sG[j][0]);
        float4 va = r[0], vb = r[1], vc = r[2], vd = r[3];
        z[0]  = fmaxf(z[0],  base[0]  + va.x);
        z[1]  = fmaxf(z[1],  base[1]  + va.y);
        z[2]  = fmaxf(z[2],  base[2]  + va.z);
        z[3]  = fmaxf(z[3],  base[3]  + va.w);
        z[4]  = fmaxf(z[4],  base[4]  + vb.x);
        z[5]  = fmaxf(z[5],  base[5]  + vb.y);
        z[6]  = fmaxf(z[6],  base[6]  + vb.z);
        z[7]  = fmaxf(z[7],  base[7]  + vb.w);
        z[8]  = fmaxf(z[8],  base[8]  + vc.x);
        z[9]  = fmaxf(z[9],  base[9]  + vc.y);
        z[10] = fmaxf(z[10], base[10] + vc.z);
        z[11] = fmaxf(z[11], base[11] + vc.w);
        z[12] = fmaxf(z[12], base[12] + vd.x);
        z[13] = fmaxf(z[13], base[13] + vd.y);
        z[14] = fmaxf(z[14], base[14] + vd.z);
        z[15] = fmaxf(z[15], base[15] + vd.w);
    }
#pragma unroll
    for (int c = 0; c < HD; ++c) fout[c] = elu_f(z[c]);
}

__global__ __launch_bounds__(512) void suep_fused(
    const float* __restrict__ x_pf,
    const float* __restrict__ W1,  const float* __restrict__ b1,
    const float* __restrict__ W2,  const float* __restrict__ b2,
    const float* __restrict__ Wc,  const float* __restrict__ bc,
    const float* __restrict__ Wo1, const float* __restrict__ bo1,
    const float* __restrict__ Wo2, const float* __restrict__ bo2,
    const float* __restrict__ Wo3, const float* __restrict__ bo3,
    float* __restrict__ out)
{
    __shared__ float sA[NP][HD];       // 32 KB node features (ping)
    __shared__ float sG[NP][GPAD];     // 40 KB neighbor projections (padded rows)
    __shared__ float sSq[NP];          // squared norms
    __shared__ float sW1[4][HD];
    __shared__ float sB1[HD];
    __shared__ float sW2[HD][HD];
    __shared__ float sB2[HD];
    __shared__ float sWcB[HD][HD];     // Wc[16:32]
    __shared__ float sWcD[HD][HD];     // Wc[0:16] - Wc[16:32]
    __shared__ float sBc[HD];
    __shared__ float sWo1[HD * 8];
    __shared__ float sBo1[8];
    __shared__ float sWo2[8 * 4];
    __shared__ float sBo2[4];
    __shared__ float sWo3[4];
    __shared__ float sBo3[1];
    __shared__ float sRed[8][HD];      // per-wave pooling partials
    __shared__ float sPool[HD];

    const int tid = threadIdx.x;
    const int ev  = blockIdx.x;

    // ---- stage all weights into LDS ----
    if (tid < 64) ((float*)sW1)[tid] = W1[tid];
    if (tid < HD) { sB1[tid] = b1[tid]; sB2[tid] = b2[tid]; sBc[tid] = bc[tid]; }
    if (tid < 256) {
        ((float*)sW2)[tid] = W2[tid];
        float wb = Wc[256 + tid];
        ((float*)sWcB)[tid] = wb;
        ((float*)sWcD)[tid] = Wc[tid] - wb;
    }
    if (tid < 128) sWo1[tid] = Wo1[tid];
    if (tid < 8)   sBo1[tid] = bo1[tid];
    if (tid < 32)  sWo2[tid] = Wo2[tid];
    if (tid < 4)   { sBo2[tid] = bo2[tid]; sWo3[tid] = Wo3[tid]; }
    if (tid == 0)  sBo3[0] = bo3[0];
    __syncthreads();

    // ---- encoder: h = elu(elu(x@W1+b1)@W2+b2) ----
    float4 xv = ((const float4*)x_pf)[ev * NP + tid];
    float t1[HD];
#pragma unroll
    for (int c = 0; c < HD; ++c) {
        float a = sB1[c];
        a = fmaf(xv.x, sW1[0][c], a);
        a = fmaf(xv.y, sW1[1][c], a);
        a = fmaf(xv.z, sW1[2][c], a);
        a = fmaf(xv.w, sW1[3][c], a);
        t1[c] = elu_f(a);
    }
    float h[HD];
    float sq = 0.0f;
#pragma unroll
    for (int c = 0; c < HD; ++c) {
        float a = sB2[c];
#pragma unroll
        for (int f = 0; f < HD; ++f) a = fmaf(t1[f], sW2[f][c], a);
        a = elu_f(a);
        h[c] = a;
        sq = fmaf(a, a, sq);
    }
    ((float4*)(&sA[tid][0]))[0] = make_float4(h[0], h[1], h[2], h[3]);
    ((float4*)(&sA[tid][0]))[1] = make_float4(h[4], h[5], h[6], h[7]);
    ((float4*)(&sA[tid][0]))[2] = make_float4(h[8], h[9], h[10], h[11]);
    ((float4*)(&sA[tid][0]))[3] = make_float4(h[12], h[13], h[14], h[15]);
    sSq[tid] = sq;
    __syncthreads();

    // ---- conv 1 ----
    float f1[HD];
    conv_pass(sA, sSq, sG, sWcB, sWcD, sBc, tid, f1);
    __syncthreads();   // all reads of sA/sG complete
    {
        float s = 0.0f;
#pragma unroll
        for (int c = 0; c < HD; ++c) s = fmaf(f1[c], f1[c], s);
        ((float4*)(&sA[tid][0]))[0] = make_float4(f1[0], f1[1], f1[2], f1[3]);
        ((float4*)(&sA[tid][0]))[1] = make_float4(f1[4], f1[5], f1[6], f1[7]);
        ((float4*)(&sA[tid][0]))[2] = make_float4(f1[8], f1[9], f1[10], f1[11]);
        ((float4*)(&sA[tid][0]))[3] = make_float4(f1[12], f1[13], f1[14], f1[15]);
        sSq[tid] = s;
    }
    __syncthreads();

    // ---- conv 2 (shared weights) ----
    float f2[HD];
    conv_pass(sA, sSq, sG, sWcB, sWcD, sBc, tid, f2);

    // ---- per-event mean pool: wave butterfly reduce, then cross-wave ----
#pragma unroll
    for (int m = 32; m >= 1; m >>= 1) {
#pragma unroll
        for (int c = 0; c < HD; ++c) f2[c] += __shfl_xor(f2[c], m, 64);
    }
    const int lane = tid & 63, wid = tid >> 6;
    if (lane == 0) {
        ((float4*)(&sRed[wid][0]))[0] = make_float4(f2[0], f2[1], f2[2], f2[3]);
        ((float4*)(&sRed[wid][0]))[1] = make_float4(f2[4], f2[5], f2[6], f2[7]);
        ((float4*)(&sRed[wid][0]))[2] = make_float4(f2[8], f2[9], f2[10], f2[11]);
        ((float4*)(&sRed[wid][0]))[3] = make_float4(f2[12], f2[13], f2[14], f2[15]);
    }
    __syncthreads();
    if (tid < HD) {
        float s = 0.0f;
#pragma unroll
        for (int w = 0; w < 8; ++w) s += sRed[w][tid];
        sPool[tid] = s * (1.0f / (float)NP);
    }
    __syncthreads();

    // ---- head MLP (thread 0) + outputs ----
    if (tid == 0) {
        float o1[8];
#pragma unroll
        for (int c = 0; c < 8; ++c) {
            float a = sBo1[c];
#pragma unroll
            for (int f = 0; f < HD; ++f) a = fmaf(sPool[f], sWo1[f * 8 + c], a);
            o1[c] = elu_f(a);
        }
        float o2[4];
#pragma unroll
        for (int c = 0; c < 4; ++c) {
            float a = sBo2[c];
#pragma unroll
            for (int f = 0; f < 8; ++f) a = fmaf(o1[f], sWo2[f * 4 + c], a);
            o2[c] = elu_f(a);
        }
        float o3 = sBo3[0];
#pragma unroll
        for (int f = 0; f < 4; ++f) o3 = fmaf(o2[f], sWo3[f], o3);
        out[ev] = o3;                  // output 0: net output [B,1]
        out[NEV + ev] = (float)ev;     // output 1: arange(B)
    }
}

extern "C" void kernel_launch(void* const* d_in, const int* in_sizes, int n_in,
                              void* d_out, int out_size, void* d_ws, size_t ws_size,
                              hipStream_t stream) {
    const float* x_pf = (const float*)d_in[0];
    // d_in[1] = batch_pf (contiguous equal-size events; unused)
    const float* W1  = (const float*)d_in[2];
    const float* b1  = (const float*)d_in[3];
    const float* W2  = (const float*)d_in[4];
    const float* b2  = (const float*)d_in[5];
    const float* Wc  = (const float*)d_in[6];
    const float* bc  = (const float*)d_in[7];
    const float* Wo1 = (const float*)d_in[8];
    const float* bo1 = (const float*)d_in[9];
    const float* Wo2 = (const float*)d_in[10];
    const float* bo2 = (const float*)d_in[11];
    const float* Wo3 = (const float*)d_in[12];
    const float* bo3 = (const float*)d_in[13];
    float* out = (float*)d_out;

    hipLaunchKernelGGL(suep_fused, dim3(NEV), dim3(512), 0, stream,
                       x_pf, W1, b1, W2, b2, Wc, bc,
                       Wo1, bo1, Wo2, bo2, Wo3, bo3, out);
}

// Round 2
// 151.401 us; speedup vs baseline: 1.6597x; 1.6597x over previous
//
#include <hip/hip_runtime.h>

#define NEV 256   // events
#define NP  512   // particles per event
#define HD  16    // hidden dim
#define GPAD 20   // padded sG row (floats)
#define KBS 36    // keybuf row stride in words (32 cols + 4 pad, keeps 16B align)

typedef short s16x8  __attribute__((ext_vector_type(8)));
typedef float f32x16 __attribute__((ext_vector_type(16)));

#define Z16 {0.f,0.f,0.f,0.f,0.f,0.f,0.f,0.f,0.f,0.f,0.f,0.f,0.f,0.f,0.f,0.f}

__device__ __forceinline__ float elu_f(float x) {
    return x > 0.0f ? x : (__expf(x) - 1.0f);
}
__device__ __forceinline__ unsigned umin_(unsigned a, unsigned b) { return a < b ? a : b; }
__device__ __forceinline__ unsigned med3u(unsigned a, unsigned b, unsigned c) {
    unsigned d;
    asm("v_med3_u32 %0, %1, %2, %3" : "=v"(d) : "v"(a), "v"(b), "v"(c));
    return d;
}
// f32 -> bf16 bits, round-to-nearest-even
__device__ __forceinline__ unsigned short rneb(float f) {
    unsigned u = __float_as_uint(f);
    return (unsigned short)((u + 0x7FFFu + ((u >> 16) & 1u)) >> 16);
}
__device__ __forceinline__ float bits2f(unsigned short b) {
    return __uint_as_float(((unsigned)b) << 16);
}

__global__ __launch_bounds__(512) void suep_fused(
    const float* __restrict__ x_pf,
    const float* __restrict__ W1,  const float* __restrict__ b1,
    const float* __restrict__ W2,  const float* __restrict__ b2,
    const float* __restrict__ Wc,  const float* __restrict__ bc,
    const float* __restrict__ Wo1, const float* __restrict__ bo1,
    const float* __restrict__ Wo2, const float* __restrict__ bo2,
    const float* __restrict__ Wo3, const float* __restrict__ bo3,
    float* __restrict__ out)
{
    // keybuf: 512 rows x 36 words = 73728 B. Aliased as sG[512][GPAD] in edge phase.
    __shared__ unsigned kb[NP * KBS];
    __shared__ s16x8 fragH[16][64];    // bf16 hi fragments, 16 KB
    __shared__ s16x8 fragL[16][64];    // bf16 lo fragments, 16 KB
    __shared__ float sSq[NP];          // |h~|^2 per node
    __shared__ float sW1[64],  sB1[HD];
    __shared__ float sW2[256], sB2[HD];
    __shared__ float sWcB[256], sWcD[256], sBc[HD];
    __shared__ float sWo1[128], sBo1[8], sWo2[32], sBo2[4], sWo3[4], sBo3[1];
    __shared__ float sRedM[8];         // per-wave max(sq) partials
    __shared__ float sRed[8][HD];      // pool partials
    __shared__ float sPool[HD];

    const int tid   = threadIdx.x;
    const int ev    = blockIdx.x;
    const int l     = tid & 63;
    const int w     = tid >> 6;        // wave id 0..7
    const int c32   = l & 31;          // col within 32-tile
    const int khalf = l >> 5;          // 0/1

    // ---- stage weights ----
    if (tid < 64) sW1[tid] = W1[tid];
    if (tid < HD) { sB1[tid] = b1[tid]; sB2[tid] = b2[tid]; sBc[tid] = bc[tid]; }
    if (tid < 256) {
        sW2[tid] = W2[tid];
        float wb = Wc[256 + tid];
        sWcB[tid] = wb;
        sWcD[tid] = Wc[tid] - wb;
    }
    if (tid < 128) sWo1[tid] = Wo1[tid];
    if (tid < 8)   sBo1[tid] = bo1[tid];
    if (tid < 32)  sWo2[tid] = Wo2[tid];
    if (tid < 4)   { sBo2[tid] = bo2[tid]; sWo3[tid] = Wo3[tid]; }
    if (tid == 0)  sBo3[0] = bo3[0];
    __syncthreads();

    // ---- encoder: h = elu(elu(x@W1+b1)@W2+b2) ----
    float4 xv = ((const float4*)x_pf)[ev * NP + tid];
    float e1[HD];
#pragma unroll
    for (int c = 0; c < HD; ++c) {
        float a = sB1[c];
        a = fmaf(xv.x, sW1[0 * HD + c], a);
        a = fmaf(xv.y, sW1[1 * HD + c], a);
        a = fmaf(xv.z, sW1[2 * HD + c], a);
        a = fmaf(xv.w, sW1[3 * HD + c], a);
        e1[c] = elu_f(a);
    }
    float h[HD];
#pragma unroll
    for (int c = 0; c < HD; ++c) {
        float a = sB2[c];
#pragma unroll
        for (int f = 0; f < HD; ++f) a = fmaf(e1[f], sW2[f * HD + c], a);
        h[c] = elu_f(a);
    }

    // ---- split h into bf16 hi/lo fragments, compute |h~|^2 and C offset ----
    // Returns C = max_event(sq) + 1 (keeps keys strictly positive).
    auto build_frags = [&](const float* hr) -> float {
        s16x8 vh0, vh1, vl0, vl1;
        float sq = 0.0f;
#pragma unroll
        for (int k = 0; k < HD; ++k) {
            unsigned short hb = rneb(hr[k]);
            float fh = bits2f(hb);
            float rr = hr[k] - fh;
            unsigned short lb = rneb(rr);
            float fl = bits2f(lb);
            float ht = fh + fl;
            sq = fmaf(ht, ht, sq);
            if (k < 8) { vh0[k] = (short)hb; vl0[k] = (short)lb; }
            else       { vh1[k - 8] = (short)hb; vl1[k - 8] = (short)lb; }
        }
        int b = tid >> 5, r = tid & 31;
        fragH[b][r]      = vh0;
        fragH[b][r + 32] = vh1;
        fragL[b][r]      = vl0;
        fragL[b][r + 32] = vl1;
        sSq[tid] = sq;
        float m = sq;
#pragma unroll
        for (int d = 32; d >= 1; d >>= 1) m = fmaxf(m, __shfl_xor(m, d, 64));
        if (l == 0) sRedM[w] = m;
        __syncthreads();
        float mx = sRedM[0];
#pragma unroll
        for (int i = 1; i < 8; ++i) mx = fmaxf(mx, sRedM[i]);
        return mx + 1.0f;
    };

    // G-tile pair for column-strip s: tiles (I=2w, s), (I=2w+1, s).
    // G = Hh.Hh^T + Hh.Hl^T + Hl.Hh^T  (error ~2^-17 relative)
    auto compute_strip = [&](int s, f32x16& a0, f32x16& a1) {
        s16x8 Bh  = fragH[s][l],         Bl  = fragL[s][l];
        s16x8 Ah0 = fragH[2 * w][l],     Al0 = fragL[2 * w][l];
        s16x8 Ah1 = fragH[2 * w + 1][l], Al1 = fragL[2 * w + 1][l];
        f32x16 z = Z16;
        a0 = __builtin_amdgcn_mfma_f32_32x32x16_bf16(Al0, Bh, z,  0, 0, 0);
        a0 = __builtin_amdgcn_mfma_f32_32x32x16_bf16(Ah0, Bl, a0, 0, 0, 0);
        a0 = __builtin_amdgcn_mfma_f32_32x32x16_bf16(Ah0, Bh, a0, 0, 0, 0);
        a1 = __builtin_amdgcn_mfma_f32_32x32x16_bf16(Al1, Bh, z,  0, 0, 0);
        a1 = __builtin_amdgcn_mfma_f32_32x32x16_bf16(Ah1, Bl, a1, 0, 0, 0);
        a1 = __builtin_amdgcn_mfma_f32_32x32x16_bf16(Ah1, Bh, a1, 0, 0, 0);
    };

    // Store packed keys: key = bits(C + sq_col - 2*G) & ~511 | col.
    // Per-row constant sq_row dropped (monotone per row). C/D layout per m74/m101:
    // col = lane&31, row = (q&3) + 8*(q>>2) + 4*(lane>>5).
    auto store_strip = [&](int s, const f32x16& a0, const f32x16& a1, float Cv) {
        float base = Cv + sSq[s * 32 + c32];
        unsigned colb = (unsigned)(s * 32 + c32);
        int rb0 = (2 * w) * 32 + 4 * khalf;
#pragma unroll
        for (int q = 0; q < 16; ++q) {
            int roff = (q & 3) + 8 * (q >> 2);
            unsigned k0 = (__float_as_uint(fmaf(-2.0f, a0[q], base)) & 0xFFFFFE00u) | colb;
            kb[(rb0 + roff) * KBS + c32] = k0;
            unsigned k1 = (__float_as_uint(fmaf(-2.0f, a1[q], base)) & 0xFFFFFE00u) | colb;
            kb[(rb0 + 32 + roff) * KBS + c32] = k1;
        }
    };

    // One full DynamicEdgeConv. hr: input features (regs). fout: output (regs).
    auto do_conv = [&](const float* hr, float* fout) {
        float Cv = build_frags(hr);   // contains one barrier

        unsigned t0 = ~0u, t1 = ~0u, t2 = ~0u, t3 = ~0u,
                 t4 = ~0u, t5 = ~0u, t6 = ~0u, t7 = ~0u;
#define INS(KEY) do { unsigned kk = (KEY);            \
        t7 = med3u(t6, kk, t7); t6 = med3u(t5, kk, t6); \
        t5 = med3u(t4, kk, t5); t4 = med3u(t3, kk, t4); \
        t3 = med3u(t2, kk, t3); t2 = med3u(t1, kk, t2); \
        t1 = med3u(t0, kk, t1); t0 = umin_(kk, t0); } while (0)

        f32x16 aA = Z16, aB = Z16, nA = Z16, nB = Z16;
        compute_strip(0, aA, aB);
        for (int s = 0; s < 16; ++s) {
            store_strip(s, aA, aB, Cv);
            __syncthreads();                       // keys of strip s visible
            if (s < 15) compute_strip(s + 1, nA, nB);   // MFMA overlaps scan
            const uint4* rp = (const uint4*)&kb[tid * KBS];
#pragma unroll
            for (int g = 0; g < 8; ++g) {
                uint4 k4 = rp[g];
                INS(k4.x); INS(k4.y); INS(k4.z); INS(k4.w);
            }
            __syncthreads();                       // scan done before overwrite
            aA = nA; aB = nB;
        }
#undef INS

        // ---- edge MLP: m_ij = elu(base_i + g_j); max over 8 nbrs; elu monotone ----
        float gg[HD], bb[HD];
#pragma unroll
        for (int c = 0; c < HD; ++c) { gg[c] = 0.0f; bb[c] = sBc[c]; }
#pragma unroll
        for (int f = 0; f < HD; ++f) {
            float hf = hr[f];
#pragma unroll
            for (int c = 0; c < HD; ++c) {
                gg[c] = fmaf(hf, sWcB[f * HD + c], gg[c]);
                bb[c] = fmaf(hf, sWcD[f * HD + c], bb[c]);
            }
        }
        float (*sG)[GPAD] = reinterpret_cast<float(*)[GPAD]>(kb);
        ((float4*)(&sG[tid][0]))[0] = make_float4(gg[0], gg[1], gg[2], gg[3]);
        ((float4*)(&sG[tid][0]))[1] = make_float4(gg[4], gg[5], gg[6], gg[7]);
        ((float4*)(&sG[tid][0]))[2] = make_float4(gg[8], gg[9], gg[10], gg[11]);
        ((float4*)(&sG[tid][0]))[3] = make_float4(gg[12], gg[13], gg[14], gg[15]);
        __syncthreads();

        int idx[8] = { (int)(t0 & 511u), (int)(t1 & 511u), (int)(t2 & 511u),
                       (int)(t3 & 511u), (int)(t4 & 511u), (int)(t5 & 511u),
                       (int)(t6 & 511u), (int)(t7 & 511u) };
        float z[HD];
#pragma unroll
        for (int c = 0; c < HD; ++c) z[c] = -3.4e38f;
#pragma unroll
        for (int n = 0; n < 8; ++n) {
            const float4* r4 = (const float4*)(&sG[idx[n]][0]);
            float4 va = r4[0], vb = r4[1], vc = r4[2], vd = r4[3];
            z[0]  = fmaxf(z[0],  bb[0]  + va.x);
            z[1]  = fmaxf(z[1],  bb[1]  + va.y);
            z[2]  = fmaxf(z[2],  bb[2]  + va.z);
            z[3]  = fmaxf(z[3],  bb[3]  + va.w);
            z[4]  = fmaxf(z[4],  bb[4]  + vb.x);
            z[5]  = fmaxf(z[5],  bb[5]  + vb.y);
            z[6]  = fmaxf(z[6],  bb[6]  + vb.z);
            z[7]  = fmaxf(z[7],  bb[7]  + vb.w);
            z[8]  = fmaxf(z[8],  bb[8]  + vc.x);
            z[9]  = fmaxf(z[9],  bb[9]  + vc.y);
            z[10] = fmaxf(z[10], bb[10] + vc.z);
            z[11] = fmaxf(z[11], bb[11] + vc.w);
            z[12] = fmaxf(z[12], bb[12] + vd.x);
            z[13] = fmaxf(z[13], bb[13] + vd.y);
            z[14] = fmaxf(z[14], bb[14] + vd.z);
            z[15] = fmaxf(z[15], bb[15] + vd.w);
        }
#pragma unroll
        for (int c = 0; c < HD; ++c) fout[c] = elu_f(z[c]);
    };

    float f1[HD], f2[HD];
    do_conv(h, f1);
    do_conv(f1, f2);

    // ---- mean pool ----
#pragma unroll
    for (int m = 32; m >= 1; m >>= 1) {
#pragma unroll
        for (int c = 0; c < HD; ++c) f2[c] += __shfl_xor(f2[c], m, 64);
    }
    if (l == 0) {
        ((float4*)(&sRed[w][0]))[0] = make_float4(f2[0], f2[1], f2[2], f2[3]);
        ((float4*)(&sRed[w][0]))[1] = make_float4(f2[4], f2[5], f2[6], f2[7]);
        ((float4*)(&sRed[w][0]))[2] = make_float4(f2[8], f2[9], f2[10], f2[11]);
        ((float4*)(&sRed[w][0]))[3] = make_float4(f2[12], f2[13], f2[14], f2[15]);
    }
    __syncthreads();
    if (tid < HD) {
        float s = 0.0f;
#pragma unroll
        for (int ww = 0; ww < 8; ++ww) s += sRed[ww][tid];
        sPool[tid] = s * (1.0f / (float)NP);
    }
    __syncthreads();

    // ---- head MLP + outputs ----
    if (tid == 0) {
        float o1[8];
#pragma unroll
        for (int c = 0; c < 8; ++c) {
            float a = sBo1[c];
#pragma unroll
            for (int f = 0; f < HD; ++f) a = fmaf(sPool[f], sWo1[f * 8 + c], a);
            o1[c] = elu_f(a);
        }
        float o2[4];
#pragma unroll
        for (int c = 0; c < 4; ++c) {
            float a = sBo2[c];
#pragma unroll
            for (int f = 0; f < 8; ++f) a = fmaf(o1[f], sWo2[f * 4 + c], a);
            o2[c] = elu_f(a);
        }
        float o3 = sBo3[0];
#pragma unroll
        for (int f = 0; f < 4; ++f) o3 = fmaf(o2[f], sWo3[f], o3);
        out[ev] = o3;
        out[NEV + ev] = (float)ev;
    }
}

extern "C" void kernel_launch(void* const* d_in, const int* in_sizes, int n_in,
                              void* d_out, int out_size, void* d_ws, size_t ws_size,
                              hipStream_t stream) {
    const float* x_pf = (const float*)d_in[0];
    // d_in[1] = batch_pf (contiguous equal-size events; unused)
    const float* W1  = (const float*)d_in[2];
    const float* b1  = (const float*)d_in[3];
    const float* W2  = (const float*)d_in[4];
    const float* b2  = (const float*)d_in[5];
    const float* Wc  = (const float*)d_in[6];
    const float* bc  = (const float*)d_in[7];
    const float* Wo1 = (const float*)d_in[8];
    const float* bo1 = (const float*)d_in[9];
    const float* Wo2 = (const float*)d_in[10];
    const float* bo2 = (const float*)d_in[11];
    const float* Wo3 = (const float*)d_in[12];
    const float* bo3 = (const float*)d_in[13];
    float* out = (float*)d_out;

    hipLaunchKernelGGL(suep_fused, dim3(NEV), dim3(512), 0, stream,
                       x_pf, W1, b1, W2, b2, Wc, bc,
                       Wo1, bo1, Wo2, bo2, Wo3, bo3, out);
}

// Round 3
// 143.173 us; speedup vs baseline: 1.7551x; 1.0575x over previous
//
#include <hip/hip_runtime.h>

#define NEV 256   // events
#define NP  512   // particles per event
#define HD  16    // hidden dim
#define GPAD 20   // padded sG row (floats)
#define KBS 36    // keybuf row stride in words (32 cols + 4 pad, keeps 16B align)

typedef short s16x8  __attribute__((ext_vector_type(8)));
typedef float f32x16 __attribute__((ext_vector_type(16)));

#define Z16 {0.f,0.f,0.f,0.f,0.f,0.f,0.f,0.f,0.f,0.f,0.f,0.f,0.f,0.f,0.f,0.f}

__device__ __forceinline__ float elu_f(float x) {
    return x > 0.0f ? x : (__expf(x) - 1.0f);
}
__device__ __forceinline__ unsigned umin_(unsigned a, unsigned b) { return a < b ? a : b; }
__device__ __forceinline__ unsigned med3u(unsigned a, unsigned b, unsigned c) {
    unsigned d;
    asm("v_med3_u32 %0, %1, %2, %3" : "=v"(d) : "v"(a), "v"(b), "v"(c));
    return d;
}
// f32 -> bf16 bits, round-to-nearest-even
__device__ __forceinline__ unsigned short rneb(float f) {
    unsigned u = __float_as_uint(f);
    return (unsigned short)((u + 0x7FFFu + ((u >> 16) & 1u)) >> 16);
}
__device__ __forceinline__ float bits2f(unsigned short b) {
    return __uint_as_float(((unsigned)b) << 16);
}

__global__ __launch_bounds__(512) void suep_fused(
    const float* __restrict__ x_pf,
    const float* __restrict__ W1,  const float* __restrict__ b1,
    const float* __restrict__ W2,  const float* __restrict__ b2,
    const float* __restrict__ Wc,  const float* __restrict__ bc,
    const float* __restrict__ Wo1, const float* __restrict__ bo1,
    const float* __restrict__ Wo2, const float* __restrict__ bo2,
    const float* __restrict__ Wo3, const float* __restrict__ bo3,
    float* __restrict__ out)
{
    // keybuf: 512 rows x 36 words = 73728 B. Aliased as sG[512][GPAD] in edge phase.
    __shared__ unsigned kb[NP * KBS];
    __shared__ s16x8 fragH[16][64];    // bf16 hi fragments, 16 KB
    __shared__ s16x8 fragL[16][64];    // bf16 lo fragments, 16 KB
    __shared__ float sSq[NP];          // |h~|^2 per node
    __shared__ float sW1[64],  sB1[HD];
    __shared__ float sW2[256], sB2[HD];
    __shared__ float sWcB[256], sWcD[256], sBc[HD];
    __shared__ float sWo1[128], sBo1[8], sWo2[32], sBo2[4], sWo3[4], sBo3[1];
    __shared__ float sRedM[8];         // per-wave max(sq) partials
    __shared__ float sRed[8][HD];      // pool partials
    __shared__ float sPool[HD];

    const int tid   = threadIdx.x;
    const int ev    = blockIdx.x;
    const int l     = tid & 63;
    const int w     = tid >> 6;        // wave id 0..7
    const int c32   = l & 31;          // col within 32-tile
    const int khalf = l >> 5;          // 0/1

    // ---- stage weights ----
    if (tid < 64) sW1[tid] = W1[tid];
    if (tid < HD) { sB1[tid] = b1[tid]; sB2[tid] = b2[tid]; sBc[tid] = bc[tid]; }
    if (tid < 256) {
        sW2[tid] = W2[tid];
        float wb = Wc[256 + tid];
        sWcB[tid] = wb;
        sWcD[tid] = Wc[tid] - wb;
    }
    if (tid < 128) sWo1[tid] = Wo1[tid];
    if (tid < 8)   sBo1[tid] = bo1[tid];
    if (tid < 32)  sWo2[tid] = Wo2[tid];
    if (tid < 4)   { sBo2[tid] = bo2[tid]; sWo3[tid] = Wo3[tid]; }
    if (tid == 0)  sBo3[0] = bo3[0];
    __syncthreads();

    // ---- encoder: h = elu(elu(x@W1+b1)@W2+b2) ----
    float4 xv = ((const float4*)x_pf)[ev * NP + tid];
    float e1[HD];
#pragma unroll
    for (int c = 0; c < HD; ++c) {
        float a = sB1[c];
        a = fmaf(xv.x, sW1[0 * HD + c], a);
        a = fmaf(xv.y, sW1[1 * HD + c], a);
        a = fmaf(xv.z, sW1[2 * HD + c], a);
        a = fmaf(xv.w, sW1[3 * HD + c], a);
        e1[c] = elu_f(a);
    }
    float h[HD];
#pragma unroll
    for (int c = 0; c < HD; ++c) {
        float a = sB2[c];
#pragma unroll
        for (int f = 0; f < HD; ++f) a = fmaf(e1[f], sW2[f * HD + c], a);
        h[c] = elu_f(a);
    }

    // ---- split h into bf16 hi/lo fragments, compute |h~|^2 and C offset ----
    // Returns C = max_event(sq) + 1 (keeps keys strictly positive).
    // Contains one barrier (BAR-A).
    auto build_frags = [&](const float* hr) -> float {
        s16x8 vh0, vh1, vl0, vl1;
        float sq = 0.0f;
#pragma unroll
        for (int k = 0; k < HD; ++k) {
            unsigned short hb = rneb(hr[k]);
            float fh = bits2f(hb);
            float rr = hr[k] - fh;
            unsigned short lb = rneb(rr);
            float fl = bits2f(lb);
            float ht = fh + fl;
            sq = fmaf(ht, ht, sq);
            if (k < 8) { vh0[k] = (short)hb; vl0[k] = (short)lb; }
            else       { vh1[k - 8] = (short)hb; vl1[k - 8] = (short)lb; }
        }
        int b = tid >> 5, r = tid & 31;
        fragH[b][r]      = vh0;
        fragH[b][r + 32] = vh1;
        fragL[b][r]      = vl0;
        fragL[b][r + 32] = vl1;
        sSq[tid] = sq;
        float m = sq;
#pragma unroll
        for (int d = 32; d >= 1; d >>= 1) m = fmaxf(m, __shfl_xor(m, d, 64));
        if (l == 0) sRedM[w] = m;
        __syncthreads();                 // BAR-A: frags + sSq + sRedM published
        float mx = sRedM[0];
#pragma unroll
        for (int i = 1; i < 8; ++i) mx = fmaxf(mx, sRedM[i]);
        return mx + 1.0f;
    };

    // One full DynamicEdgeConv. hr: input features (regs). fout: output (regs).
    auto do_conv = [&](const float* hr, float* fout) {
        float Cv = build_frags(hr);   // BAR-A inside

        // Hoist this wave's A-fragments (rows 64w..64w+63) — strip-invariant.
        s16x8 Ah0 = fragH[2 * w][l],     Al0 = fragL[2 * w][l];
        s16x8 Ah1 = fragH[2 * w + 1][l], Al1 = fragL[2 * w + 1][l];

        unsigned t0 = ~0u, t1 = ~0u, t2 = ~0u, t3 = ~0u,
                 t4 = ~0u, t5 = ~0u, t6 = ~0u, t7 = ~0u;
#define INS(KEY) do { unsigned kk = (KEY);            \
        t7 = med3u(t6, kk, t7); t6 = med3u(t5, kk, t6); \
        t5 = med3u(t4, kk, t5); t4 = med3u(t3, kk, t4); \
        t3 = med3u(t2, kk, t3); t2 = med3u(t1, kk, t2); \
        t1 = med3u(t0, kk, t1); t0 = umin_(kk, t0); } while (0)

        // G = Hh.Hh^T + Hh.Hl^T + Hl.Hh^T  (error ~2^-17 relative)
        auto cs = [&](int s, f32x16& a0, f32x16& a1) {
            s16x8 Bh = fragH[s][l], Bl = fragL[s][l];
            f32x16 z = Z16;
            a0 = __builtin_amdgcn_mfma_f32_32x32x16_bf16(Al0, Bh, z,  0, 0, 0);
            a0 = __builtin_amdgcn_mfma_f32_32x32x16_bf16(Ah0, Bl, a0, 0, 0, 0);
            a0 = __builtin_amdgcn_mfma_f32_32x32x16_bf16(Ah0, Bh, a0, 0, 0, 0);
            a1 = __builtin_amdgcn_mfma_f32_32x32x16_bf16(Al1, Bh, z,  0, 0, 0);
            a1 = __builtin_amdgcn_mfma_f32_32x32x16_bf16(Ah1, Bl, a1, 0, 0, 0);
            a1 = __builtin_amdgcn_mfma_f32_32x32x16_bf16(Ah1, Bh, a1, 0, 0, 0);
        };

        // Store packed keys: key = bits(C + sq_col - 2*G) & ~511 | col.
        // C/D layout (m74/m101): col = lane&31, row = (q&3)+8*(q>>2)+4*(lane>>5).
        // Wave w writes ONLY rows [64w, 64w+64) — its own scan rows.
        unsigned* wp = &kb[(64 * w + 4 * khalf) * KBS + c32];
        auto st = [&](int s, const f32x16& a0, const f32x16& a1) {
            float base = Cv + sSq[s * 32 + c32];
            unsigned colb = (unsigned)(s * 32 + c32);
#pragma unroll
            for (int q = 0; q < 16; ++q) {
                const int roff = (q & 3) + 8 * (q >> 2);
                wp[roff * KBS] =
                    (__float_as_uint(fmaf(-2.0f, a0[q], base)) & 0xFFFFFE00u) | colb;
                wp[(32 + roff) * KBS] =
                    (__float_as_uint(fmaf(-2.0f, a1[q], base)) & 0xFFFFFE00u) | colb;
            }
        };

        const uint4* rp = (const uint4*)&kb[tid * KBS];
        auto scan = [&]() {
#pragma unroll
            for (int g = 0; g < 8; ++g) {
                uint4 k4 = rp[g];
                INS(k4.x); INS(k4.y); INS(k4.z); INS(k4.w);
            }
        };

        // Barrier-free strip loop: producer wave == consumer wave for every row.
        // Intra-wave DS ordering + lgkmcnt(0) is sufficient.
        f32x16 aA, aB, nA, nB;
        cs(0, aA, aB);
        for (int s = 0; s < 16; s += 2) {
            st(s, aA, aB);
            cs(s + 1, nA, nB);                        // MFMA overlaps scan below
            asm volatile("s_waitcnt lgkmcnt(0)" ::: "memory");
            scan();
            st(s + 1, nA, nB);
            if (s + 2 < 16) cs(s + 2, aA, aB);
            asm volatile("s_waitcnt lgkmcnt(0)" ::: "memory");
            scan();
        }
#undef INS

        // ---- edge MLP: m_ij = elu(base_i + g_j); max over 8 nbrs; elu monotone ----
        float gg[HD], bb[HD];
#pragma unroll
        for (int c = 0; c < HD; ++c) { gg[c] = 0.0f; bb[c] = sBc[c]; }
#pragma unroll
        for (int f = 0; f < HD; ++f) {
            float hf = hr[f];
#pragma unroll
            for (int c = 0; c < HD; ++c) {
                gg[c] = fmaf(hf, sWcB[f * HD + c], gg[c]);
                bb[c] = fmaf(hf, sWcD[f * HD + c], bb[c]);
            }
        }
        __syncthreads();                 // BAR-B: all scans done before kb->sG alias
        float (*sG)[GPAD] = reinterpret_cast<float(*)[GPAD]>(kb);
        ((float4*)(&sG[tid][0]))[0] = make_float4(gg[0], gg[1], gg[2], gg[3]);
        ((float4*)(&sG[tid][0]))[1] = make_float4(gg[4], gg[5], gg[6], gg[7]);
        ((float4*)(&sG[tid][0]))[2] = make_float4(gg[8], gg[9], gg[10], gg[11]);
        ((float4*)(&sG[tid][0]))[3] = make_float4(gg[12], gg[13], gg[14], gg[15]);
        __syncthreads();                 // BAR-C: sG published

        int idx[8] = { (int)(t0 & 511u), (int)(t1 & 511u), (int)(t2 & 511u),
                       (int)(t3 & 511u), (int)(t4 & 511u), (int)(t5 & 511u),
                       (int)(t6 & 511u), (int)(t7 & 511u) };
        float z[HD];
#pragma unroll
        for (int c = 0; c < HD; ++c) z[c] = -3.4e38f;
#pragma unroll
        for (int n = 0; n < 8; ++n) {
            const float4* r4 = (const float4*)(&sG[idx[n]][0]);
            float4 va = r4[0], vb = r4[1], vc = r4[2], vd = r4[3];
            z[0]  = fmaxf(z[0],  bb[0]  + va.x);
            z[1]  = fmaxf(z[1],  bb[1]  + va.y);
            z[2]  = fmaxf(z[2],  bb[2]  + va.z);
            z[3]  = fmaxf(z[3],  bb[3]  + va.w);
            z[4]  = fmaxf(z[4],  bb[4]  + vb.x);
            z[5]  = fmaxf(z[5],  bb[5]  + vb.y);
            z[6]  = fmaxf(z[6],  bb[6]  + vb.z);
            z[7]  = fmaxf(z[7],  bb[7]  + vb.w);
            z[8]  = fmaxf(z[8],  bb[8]  + vc.x);
            z[9]  = fmaxf(z[9],  bb[9]  + vc.y);
            z[10] = fmaxf(z[10], bb[10] + vc.z);
            z[11] = fmaxf(z[11], bb[11] + vc.w);
            z[12] = fmaxf(z[12], bb[12] + vd.x);
            z[13] = fmaxf(z[13], bb[13] + vd.y);
            z[14] = fmaxf(z[14], bb[14] + vd.z);
            z[15] = fmaxf(z[15], bb[15] + vd.w);
        }
#pragma unroll
        for (int c = 0; c < HD; ++c) fout[c] = elu_f(z[c]);
    };

    float f1[HD], f2[HD];
    do_conv(h, f1);
    do_conv(f1, f2);

    // ---- mean pool ----
#pragma unroll
    for (int m = 32; m >= 1; m >>= 1) {
#pragma unroll
        for (int c = 0; c < HD; ++c) f2[c] += __shfl_xor(f2[c], m, 64);
    }
    if (l == 0) {
        ((float4*)(&sRed[w][0]))[0] = make_float4(f2[0], f2[1], f2[2], f2[3]);
        ((float4*)(&sRed[w][0]))[1] = make_float4(f2[4], f2[5], f2[6], f2[7]);
        ((float4*)(&sRed[w][0]))[2] = make_float4(f2[8], f2[9], f2[10], f2[11]);
        ((float4*)(&sRed[w][0]))[3] = make_float4(f2[12], f2[13], f2[14], f2[15]);
    }
    __syncthreads();
    if (tid < HD) {
        float s = 0.0f;
#pragma unroll
        for (int ww = 0; ww < 8; ++ww) s += sRed[ww][tid];
        sPool[tid] = s * (1.0f / (float)NP);
    }
    __syncthreads();

    // ---- head MLP + outputs ----
    if (tid == 0) {
        float o1[8];
#pragma unroll
        for (int c = 0; c < 8; ++c) {
            float a = sBo1[c];
#pragma unroll
            for (int f = 0; f < HD; ++f) a = fmaf(sPool[f], sWo1[f * 8 + c], a);
            o1[c] = elu_f(a);
        }
        float o2[4];
#pragma unroll
        for (int c = 0; c < 4; ++c) {
            float a = sBo2[c];
#pragma unroll
            for (int f = 0; f < 8; ++f) a = fmaf(o1[f], sWo2[f * 4 + c], a);
            o2[c] = elu_f(a);
        }
        float o3 = sBo3[0];
#pragma unroll
        for (int f = 0; f < 4; ++f) o3 = fmaf(o2[f], sWo3[f], o3);
        out[ev] = o3;
        out[NEV + ev] = (float)ev;
    }
}

extern "C" void kernel_launch(void* const* d_in, const int* in_sizes, int n_in,
                              void* d_out, int out_size, void* d_ws, size_t ws_size,
                              hipStream_t stream) {
    const float* x_pf = (const float*)d_in[0];
    // d_in[1] = batch_pf (contiguous equal-size events; unused)
    const float* W1  = (const float*)d_in[2];
    const float* b1  = (const float*)d_in[3];
    const float* W2  = (const float*)d_in[4];
    const float* b2  = (const float*)d_in[5];
    const float* Wc  = (const float*)d_in[6];
    const float* bc  = (const float*)d_in[7];
    const float* Wo1 = (const float*)d_in[8];
    const float* bo1 = (const float*)d_in[9];
    const float* Wo2 = (const float*)d_in[10];
    const float* bo2 = (const float*)d_in[11];
    const float* Wo3 = (const float*)d_in[12];
    const float* bo3 = (const float*)d_in[13];
    float* out = (float*)d_out;

    hipLaunchKernelGGL(suep_fused, dim3(NEV), dim3(512), 0, stream,
                       x_pf, W1, b1, W2, b2, Wc, bc,
                       Wo1, bo1, Wo2, bo2, Wo3, bo3, out);
}